// Round 1
// baseline (39.781 us; speedup 1.0000x reference)
//
#include <hip/hip_runtime.h>

#define PAD_VAL 9999.0f
constexpr int BATCH = 8;
constexpr int NS = 1024;      // support rows
constexpr int NQROW = 1024;   // query rows
constexpr int NF = 32;        // features
constexpr int NQUANT = 999;   // quantile count
constexpr int NCOL = BATCH * NF;          // 256 columns
constexpr int QSTRIDE = 1024;             // ws stride per column

// ---------------- K0: classify mask layout, normalize mask, seq_len ----------------
__global__ void mask_kernel(const unsigned char* mraw, unsigned char* maskN, float* seqlen) {
    __shared__ int flag3f, flagOff;
    __shared__ int cnt[BATCH];
    int t = threadIdx.x;
    if (t == 0) { flag3f = 0; flagOff = 0; }
    if (t < BATCH) cnt[t] = 0;
    __syncthreads();
    // Only read the first BATCH*NS bytes: safe whether the buffer holds
    // 1-byte bools (exactly that size) or int32/f32 (larger).
    int l3f = 0, loff = 0;
    for (int i = t; i < BATCH * NS; i += blockDim.x) {
        unsigned char v = mraw[i];
        int r = i & 3;
        if (r == 3 && v == 0x3f) l3f = 1;          // f32 1.0 pattern
        if (r != 0 && v != 0)    loff = 1;         // impossible for int32 0/1
    }
    if (l3f)  atomicOr(&flag3f, 1);
    if (loff) atomicOr(&flagOff, 1);
    __syncthreads();
    int mode = flag3f ? 2 : (flagOff ? 1 : 0);     // 2=f32, 1=byte-bool, 0=int32
    for (int i = t; i < BATCH * NS; i += blockDim.x) {
        int m;
        if (mode == 1)      m = (mraw[i] != 0);
        else if (mode == 0) m = (((const int*)mraw)[i] != 0);
        else                m = (((const float*)mraw)[i] != 0.0f);
        maskN[i] = (unsigned char)m;
        if (!m) atomicAdd(&cnt[i >> 10], 1);       // i>>10 == batch index (NS=1024)
    }
    __syncthreads();
    if (t < BATCH) seqlen[t] = (float)cnt[t];
}

// ---------------- K1: per-column bitonic sort + 999 quantiles ----------------
__global__ __launch_bounds__(1024) void sortquant_kernel(const float* xs,
                                                         const unsigned char* maskN,
                                                         float* quant) {
    __shared__ float s[NS];
    int col = blockIdx.x;            // b*NF + f
    int b = col >> 5, f = col & 31;
    int i = threadIdx.x;             // 1024 threads, one element each
    float v = maskN[b * NS + i] ? PAD_VAL : xs[(b * NS + i) * NF + f];
    s[i] = v;
    for (int k = 2; k <= NS; k <<= 1) {
        for (int j = k >> 1; j > 0; j >>= 1) {
            __syncthreads();
            int ixj = i ^ j;
            if (ixj > i) {
                float a = s[i], c = s[ixj];
                bool up = ((i & k) == 0);
                if ((a > c) == up) { s[i] = c; s[ixj] = a; }
            }
        }
    }
    __syncthreads();
    if (i < NQUANT) {
        // replicate reference f32 arithmetic exactly
        float q = (float)(i + 1) / 1000.0f;
        float idxf = q * (float)(NS - 1);
        int lo = (int)idxf;
        int hi = min(lo + 1, NS - 1);
        float frac = idxf - (float)lo;
        quant[col * QSTRIDE + i] = s[lo] + frac * (s[hi] - s[lo]);
    }
}

// ---------------- K2: bucketize + stats + standardized outputs ----------------
__global__ __launch_bounds__(256) void bucket_kernel(const float* xs, const float* xq,
                                                     const unsigned char* maskN,
                                                     const float* quant, const float* seqlen,
                                                     float* outS, float* outQ) {
    __shared__ float q[NQUANT];
    __shared__ float vbuf[NS];
    __shared__ float rs[4], rq[4];
    int col = blockIdx.x;
    int b = col >> 5, f = col & 31;
    int t = threadIdx.x;
    const float* qc = quant + col * QSTRIDE;
    for (int k = t; k < NQUANT; k += 256) q[k] = qc[k];
    float sl = seqlen[b];
    __syncthreads();

    float sum = 0.0f, sumsq = 0.0f;
    #pragma unroll
    for (int r = 0; r < 4; r++) {
        int i = t + r * 256;
        float v = 0.0f;
        if (!maskN[b * NS + i]) {
            float x = xs[(b * NS + i) * NF + f];
            int lo = 0, hi = NQUANT;
            while (lo < hi) { int mid = (lo + hi) >> 1; if (q[mid] <= x) lo = mid + 1; else hi = mid; }
            v = (float)lo / sl;
        }
        vbuf[i] = v;
        sum += v; sumsq += v * v;
    }
    // reduce over 256 threads: wave64 shfl then cross-wave via LDS
    #pragma unroll
    for (int o = 32; o > 0; o >>= 1) {
        sum   += __shfl_down(sum, o);
        sumsq += __shfl_down(sumsq, o);
    }
    int wid = t >> 6, lane = t & 63;
    if (lane == 0) { rs[wid] = sum; rq[wid] = sumsq; }
    __syncthreads();
    if (t == 0) {
        float S = rs[0] + rs[1] + rs[2] + rs[3];
        float Q = rq[0] + rq[1] + rq[2] + rq[3];
        float mean = S / sl;
        float var = fmaxf(Q / sl - mean * mean, 0.0f);
        rs[0] = mean;
        rq[0] = (var > 0.0f) ? (1.0f / sqrtf(var)) : 0.0f;
    }
    __syncthreads();
    float mean = rs[0], istd = rq[0];

    #pragma unroll
    for (int r = 0; r < 4; r++) {
        int i = t + r * 256;
        float o = maskN[b * NS + i] ? 0.0f : (vbuf[i] - mean) * istd;
        outS[(b * NS + i) * NF + f] = o;
    }
    #pragma unroll
    for (int r = 0; r < 4; r++) {
        int i = t + r * 256;
        float x = xq[(b * NQROW + i) * NF + f];
        int lo = 0, hi = NQUANT;
        while (lo < hi) { int mid = (lo + hi) >> 1; if (q[mid] <= x) lo = mid + 1; else hi = mid; }
        float vq = (float)lo / sl;
        outQ[(b * NQROW + i) * NF + f] = (vq - mean) * istd;
    }
}

extern "C" void kernel_launch(void* const* d_in, const int* in_sizes, int n_in,
                              void* d_out, int out_size, void* d_ws, size_t ws_size,
                              hipStream_t stream) {
    const float* xs = (const float*)d_in[0];
    const float* xq = (const float*)d_in[1];
    const unsigned char* mraw = (const unsigned char*)d_in[2];
    float* out = (float*)d_out;

    // workspace layout
    float* quant = (float*)d_ws;                                   // 256*1024*4 = 1 MiB
    unsigned char* maskN = (unsigned char*)d_ws + NCOL * QSTRIDE * 4;   // 8 KiB
    float* seqlen = (float*)((char*)d_ws + NCOL * QSTRIDE * 4 + BATCH * NS); // 32 B

    mask_kernel<<<1, 256, 0, stream>>>(mraw, maskN, seqlen);
    sortquant_kernel<<<NCOL, 1024, 0, stream>>>(xs, maskN, quant);
    bucket_kernel<<<NCOL, 256, 0, stream>>>(xs, xq, maskN, quant, seqlen,
                                            out, out + BATCH * NS * NF);
}

// Round 2
// 24.067 us; speedup vs baseline: 1.6529x; 1.6529x over previous
//
#include <hip/hip_runtime.h>

#define PAD_VAL 9999.0f
constexpr int BATCH = 8;
constexpr int NS = 1024;      // support rows
constexpr int NQROW = 1024;   // query rows
constexpr int NF = 32;        // features
constexpr int NQUANT = 999;   // quantile count
constexpr int NCOL = BATCH * NF;          // 256 columns

// One block per (b,f) column. 1024 threads = 16 waves.
// Phase 1: mask-mode detect + seq_len (per block, from L2-cached 8KB).
// Phase 2: bitonic sort, 1 elem/thread; j<64 via shfl_xor (no barrier),
//          j>=64 via double-buffered LDS (1 barrier per stage, 10 total).
// Phase 3: quantiles (exact reference f32 arithmetic) into LDS.
// Phase 4: bucketize support+query (binary search), stats, standardized writes.
__global__ __launch_bounds__(1024) void fused_kernel(const float* __restrict__ xs,
                                                     const float* __restrict__ xq,
                                                     const unsigned char* __restrict__ mraw,
                                                     float* __restrict__ outS,
                                                     float* __restrict__ outQ) {
    __shared__ float s0[NS];
    __shared__ float s1[NS];          // double buffer; reused for quantile table
    __shared__ float red_s[16], red_q[16];
    __shared__ float bc[2];           // mean, istd
    __shared__ int   iflags[2];       // [0]=f32 pattern, [1]=byte-bool pattern
    __shared__ int   slen_sh;

    const int col = blockIdx.x;
    const int b = col >> 5, f = col & 31;
    const int i = threadIdx.x;
    const int wid = i >> 6, lane = i & 63;

    // ---- Phase 1a: classify mask layout from first 8192 bytes (safe for all layouts) ----
    if (i < 2) iflags[i] = 0;
    if (i == 0) slen_sh = 0;
    __syncthreads();
    {
        int l3f = 0, loff = 0;
        #pragma unroll
        for (int r = 0; r < 8; r++) {
            int idx = i * 8 + r;               // covers 0..8191
            unsigned char vb = mraw[idx];
            int m4 = idx & 3;
            if (m4 == 3 && vb == 0x3f) l3f = 1;   // f32 1.0f high byte
            if (m4 != 0 && vb != 0)    loff = 1;  // impossible for int32 0/1
        }
        if (__ballot(l3f)  && lane == 0) atomicOr(&iflags[0], 1);
        if (__ballot(loff) && lane == 0) atomicOr(&iflags[1], 1);
    }
    __syncthreads();
    const int mode = iflags[0] ? 2 : (iflags[1] ? 1 : 0);

    // ---- Phase 1b: own mask bit + seq_len (count of non-masked rows in batch b) ----
    int m;
    if (mode == 1)      m = (mraw[b * NS + i] != 0);
    else if (mode == 0) m = (((const int*)mraw)[b * NS + i] != 0);
    else                m = (((const float*)mraw)[b * NS + i] != 0.0f);
    {
        unsigned long long bal = __ballot(m == 0);
        if (lane == 0) atomicAdd(&slen_sh, __popcll(bal));
    }

    // ---- Phase 2: load support value, bitonic sort ----
    const float xsv = xs[(b * NS + i) * NF + f];
    float v = m ? PAD_VAL : xsv;

    int p = 0;
    for (int k = 2; k <= NS; k <<= 1) {
        const bool dir = ((i & k) == 0);
        for (int j = k >> 1; j > 0; j >>= 1) {
            float other;
            if (j >= 64) {
                float* buf = p ? s1 : s0;
                buf[i] = v;
                __syncthreads();
                other = buf[i ^ j];
                p ^= 1;
            } else {
                other = __shfl_xor(v, j, 64);
            }
            const bool lower = ((i & j) == 0);
            v = (lower == dir) ? fminf(v, other) : fmaxf(v, other);
        }
    }
    // sorted array into s0
    __syncthreads();                 // protect s0 vs last LDS-stage readers
    s0[i] = v;
    __syncthreads();

    // ---- Phase 3: quantiles (exact reference f32 arithmetic) into s1 ----
    if (i < NQUANT) {
        float q = (float)(i + 1) / 1000.0f;
        float idxf = q * (float)(NS - 1);
        int lo = (int)idxf;
        int hi = min(lo + 1, NS - 1);
        float frac = idxf - (float)lo;
        s1[i] = s0[lo] + frac * (s0[hi] - s0[lo]);
    }
    __syncthreads();

    const float sl = (float)slen_sh;

    // ---- Phase 4a: bucketize own support row (masked rows -> 0), reduce stats ----
    float vsup = 0.0f;
    if (!m) {
        int lo = 0, hi = NQUANT;
        while (lo < hi) { int mid = (lo + hi) >> 1; if (s1[mid] <= xsv) lo = mid + 1; else hi = mid; }
        vsup = (float)lo / sl;
    }
    float sum = vsup, sumsq = vsup * vsup;
    #pragma unroll
    for (int o = 32; o > 0; o >>= 1) {
        sum   += __shfl_down(sum, o);
        sumsq += __shfl_down(sumsq, o);
    }
    if (lane == 0) { red_s[wid] = sum; red_q[wid] = sumsq; }
    __syncthreads();
    if (i == 0) {
        float S = 0.0f, Q = 0.0f;
        #pragma unroll
        for (int w = 0; w < 16; w++) { S += red_s[w]; Q += red_q[w]; }
        float mean = S / sl;
        float var = fmaxf(Q / sl - mean * mean, 0.0f);
        bc[0] = mean;
        bc[1] = (var > 0.0f) ? (1.0f / sqrtf(var)) : 0.0f;
    }
    __syncthreads();
    const float mean = bc[0], istd = bc[1];

    // ---- Phase 4b: standardized support output ----
    outS[(b * NS + i) * NF + f] = m ? 0.0f : (vsup - mean) * istd;

    // ---- Phase 4c: query bucketize + output ----
    {
        const float xqv = xq[(b * NQROW + i) * NF + f];
        int lo = 0, hi = NQUANT;
        while (lo < hi) { int mid = (lo + hi) >> 1; if (s1[mid] <= xqv) lo = mid + 1; else hi = mid; }
        float vq = (float)lo / sl;
        outQ[(b * NQROW + i) * NF + f] = (vq - mean) * istd;
    }
}

extern "C" void kernel_launch(void* const* d_in, const int* in_sizes, int n_in,
                              void* d_out, int out_size, void* d_ws, size_t ws_size,
                              hipStream_t stream) {
    const float* xs = (const float*)d_in[0];
    const float* xq = (const float*)d_in[1];
    const unsigned char* mraw = (const unsigned char*)d_in[2];
    float* out = (float*)d_out;

    fused_kernel<<<NCOL, 1024, 0, stream>>>(xs, xq, mraw,
                                            out, out + BATCH * NS * NF);
}